// Round 1
// baseline (5170.109 us; speedup 1.0000x reference)
//
#include <hip/hip_runtime.h>
#include <math.h>

#define B_  32
#define T_  48
#define H_  1024
#define D_  512
#define V_  32000
#define G4  4096   // 4*H
#define LBLK 512   // blocks in fused LSTM (each owns 2 h-values x 4 gates = 8 W_hh rows)

// ---------------------------------------------------------------------------
// Tiled fp32 GEMM #1: x_gates.  (unchanged)
//   out xg[r = t*B+b][n] = dot(embedding[tok(b,t)], W_ih[n]) + b_ih[n]+b_hh[n]
//   M=1536, N=4096, K=512. 128x128 tile, BK=16, 256 thr, 8x8 microtile (4+4).
// ---------------------------------------------------------------------------
__global__ __launch_bounds__(256)
void gemm_xg(const int* __restrict__ sent_inputs,
             const float* __restrict__ embedding,
             const float* __restrict__ W_ih,
             const float* __restrict__ b_ih,
             const float* __restrict__ b_hh,
             float* __restrict__ xg)
{
    __shared__ float As[16][132];
    __shared__ float Bs[16][132];
    __shared__ int   rowoff[128];

    const int tid = threadIdx.x;
    const int rb  = blockIdx.x * 128;
    const int nb  = blockIdx.y * 128;

    if (tid < 128) {
        int r   = rb + tid;
        int t   = r >> 5;
        int b   = r & 31;
        int tok = sent_inputs[b * T_ + t];
        rowoff[tid] = tok * D_;
    }
    __syncthreads();

    const int ty = tid >> 4, tx = tid & 15;
    float acc[8][8];
#pragma unroll
    for (int i = 0; i < 8; ++i)
#pragma unroll
        for (int j = 0; j < 8; ++j) acc[i][j] = 0.f;

    for (int it = 0; it < D_ / 16; ++it) {
        const int k0 = it * 16;
        __syncthreads();
#pragma unroll
        for (int j = 0; j < 2; ++j) {
            int i  = tid + j * 256;
            int m  = i >> 2;
            int kk = (i & 3) << 2;
            float4 av = *reinterpret_cast<const float4*>(embedding + rowoff[m] + k0 + kk);
            As[kk+0][m] = av.x; As[kk+1][m] = av.y; As[kk+2][m] = av.z; As[kk+3][m] = av.w;
            float4 bv = *reinterpret_cast<const float4*>(W_ih + (size_t)(nb + m) * D_ + k0 + kk);
            Bs[kk+0][m] = bv.x; Bs[kk+1][m] = bv.y; Bs[kk+2][m] = bv.z; Bs[kk+3][m] = bv.w;
        }
        __syncthreads();
#pragma unroll
        for (int kk = 0; kk < 16; ++kk) {
            float4 a0 = *reinterpret_cast<const float4*>(&As[kk][ty * 4]);
            float4 a1 = *reinterpret_cast<const float4*>(&As[kk][64 + ty * 4]);
            float4 b0 = *reinterpret_cast<const float4*>(&Bs[kk][tx * 4]);
            float4 b1 = *reinterpret_cast<const float4*>(&Bs[kk][64 + tx * 4]);
            float a[8] = {a0.x,a0.y,a0.z,a0.w,a1.x,a1.y,a1.z,a1.w};
            float b[8] = {b0.x,b0.y,b0.z,b0.w,b1.x,b1.y,b1.z,b1.w};
#pragma unroll
            for (int i = 0; i < 8; ++i)
#pragma unroll
                for (int j = 0; j < 8; ++j) acc[i][j] = fmaf(a[i], b[j], acc[i][j]);
        }
    }

    float bias[8];
#pragma unroll
    for (int j = 0; j < 8; ++j) {
        int n = nb + ((j < 4) ? tx * 4 + j : 64 + tx * 4 + (j - 4));
        bias[j] = b_ih[n] + b_hh[n];
    }
#pragma unroll
    for (int i = 0; i < 8; ++i) {
        int m = (i < 4) ? ty * 4 + i : 64 + ty * 4 + (i - 4);
        int r = rb + m;
        float* op = xg + (size_t)r * G4 + nb;
        float4 v0 = make_float4(acc[i][0]+bias[0], acc[i][1]+bias[1],
                                acc[i][2]+bias[2], acc[i][3]+bias[3]);
        float4 v1 = make_float4(acc[i][4]+bias[4], acc[i][5]+bias[5],
                                acc[i][6]+bias[6], acc[i][7]+bias[7]);
        *reinterpret_cast<float4*>(op + tx * 4)      = v0;
        *reinterpret_cast<float4*>(op + 64 + tx * 4) = v1;
    }
}

// ---------------------------------------------------------------------------
// Tiled fp32 GEMM #2: logits.  (unchanged)
// ---------------------------------------------------------------------------
__global__ __launch_bounds__(256)
void gemm_logits(const float* __restrict__ hs,
                 const float* __restrict__ W_out,
                 const float* __restrict__ b_out,
                 float* __restrict__ out)
{
    __shared__ float As[16][132];
    __shared__ float Bs[16][132];
    __shared__ int   rowoff[128];

    const int tid = threadIdx.x;
    const int rb  = blockIdx.x * 128;
    const int nb  = blockIdx.y * 128;

    if (tid < 128) {
        int r = rb + tid;
        int b = r / T_;
        int t = r - b * T_;
        rowoff[tid] = (t * B_ + b) * H_;
    }
    __syncthreads();

    const int ty = tid >> 4, tx = tid & 15;
    float acc[8][8];
#pragma unroll
    for (int i = 0; i < 8; ++i)
#pragma unroll
        for (int j = 0; j < 8; ++j) acc[i][j] = 0.f;

    for (int it = 0; it < H_ / 16; ++it) {
        const int k0 = it * 16;
        __syncthreads();
#pragma unroll
        for (int j = 0; j < 2; ++j) {
            int i  = tid + j * 256;
            int m  = i >> 2;
            int kk = (i & 3) << 2;
            float4 av = *reinterpret_cast<const float4*>(hs + rowoff[m] + k0 + kk);
            As[kk+0][m] = av.x; As[kk+1][m] = av.y; As[kk+2][m] = av.z; As[kk+3][m] = av.w;
            float4 bv = *reinterpret_cast<const float4*>(W_out + (size_t)(nb + m) * H_ + k0 + kk);
            Bs[kk+0][m] = bv.x; Bs[kk+1][m] = bv.y; Bs[kk+2][m] = bv.z; Bs[kk+3][m] = bv.w;
        }
        __syncthreads();
#pragma unroll
        for (int kk = 0; kk < 16; ++kk) {
            float4 a0 = *reinterpret_cast<const float4*>(&As[kk][ty * 4]);
            float4 a1 = *reinterpret_cast<const float4*>(&As[kk][64 + ty * 4]);
            float4 b0 = *reinterpret_cast<const float4*>(&Bs[kk][tx * 4]);
            float4 b1 = *reinterpret_cast<const float4*>(&Bs[kk][64 + tx * 4]);
            float a[8] = {a0.x,a0.y,a0.z,a0.w,a1.x,a1.y,a1.z,a1.w};
            float b[8] = {b0.x,b0.y,b0.z,b0.w,b1.x,b1.y,b1.z,b1.w};
#pragma unroll
            for (int i = 0; i < 8; ++i)
#pragma unroll
                for (int j = 0; j < 8; ++j) acc[i][j] = fmaf(a[i], b[j], acc[i][j]);
        }
    }

    float bias[8];
#pragma unroll
    for (int j = 0; j < 8; ++j) {
        int n = nb + ((j < 4) ? tx * 4 + j : 64 + tx * 4 + (j - 4));
        bias[j] = b_out[n];
    }
#pragma unroll
    for (int i = 0; i < 8; ++i) {
        int m = (i < 4) ? ty * 4 + i : 64 + ty * 4 + (i - 4);
        int r = rb + m;
        float* op = out + (size_t)r * V_ + nb;
        float4 v0 = make_float4(acc[i][0]+bias[0], acc[i][1]+bias[1],
                                acc[i][2]+bias[2], acc[i][3]+bias[3]);
        float4 v1 = make_float4(acc[i][4]+bias[4], acc[i][5]+bias[5],
                                acc[i][6]+bias[6], acc[i][7]+bias[7]);
        *reinterpret_cast<float4*>(op + tx * 4)      = v0;
        *reinterpret_cast<float4*>(op + 64 + tx * 4) = v1;
    }
}

// ---------------------------------------------------------------------------
// Device-wide sense-reversal barrier (agent-scope atomics; blocks guaranteed
// co-resident by the cooperative launch). cnt=bar[0], gen=bar[1].
// ---------------------------------------------------------------------------
__device__ __forceinline__ void grid_barrier(unsigned* cnt, unsigned* gen)
{
    __syncthreads();
    if (threadIdx.x == 0) {
        __threadfence();   // flush this block's writes to device scope
        unsigned g = __hip_atomic_load(gen, __ATOMIC_RELAXED, __HIP_MEMORY_SCOPE_AGENT);
        unsigned a = __hip_atomic_fetch_add(cnt, 1u, __ATOMIC_ACQ_REL, __HIP_MEMORY_SCOPE_AGENT);
        if (a == LBLK - 1) {
            __hip_atomic_store(cnt, 0u, __ATOMIC_RELAXED, __HIP_MEMORY_SCOPE_AGENT);
            __hip_atomic_store(gen, g + 1u, __ATOMIC_RELEASE, __HIP_MEMORY_SCOPE_AGENT);
        } else {
            while (__hip_atomic_load(gen, __ATOMIC_RELAXED, __HIP_MEMORY_SCOPE_AGENT) == g)
                __builtin_amdgcn_s_sleep(2);
        }
        __threadfence();   // acquire side: discard stale cached data
    }
    __syncthreads();
}

// ---------------------------------------------------------------------------
// Persistent fused LSTM: all 48 steps in one cooperative kernel.
// 512 blocks x 256 thr. Block owns h0=blockIdx*2 (2 h-values x 4 gates =
// 8 W_hh rows), pinned in LDS for the whole recurrence ([8][1028] pad ->
// conflict-free ds_read_b128; 8 lanes/row broadcast). cx lives in LDS.
// hx ping-pongs hx0<->hx1 in global (L2-resident, 128 KB).
// Thread (nl = tid&7, b = tid>>3): one (gate-row, batch) dot per step —
// float4 component FMA chains over ascending k, final (x+y)+(z+w):
// bit-identical to the previous per-step kernel.
// ---------------------------------------------------------------------------
__global__ __launch_bounds__(256)
void lstm_fused(const float* __restrict__ W_hh,
                const float* __restrict__ xg,
                const float* __restrict__ hidden_state,
                const int* __restrict__ sent_len,
                float* __restrict__ hs,
                float* __restrict__ hx0,
                float* __restrict__ hx1,
                unsigned* __restrict__ bar)
{
    __shared__ float Wl[8][1028];   // pad 1028: row base bank = 4*nl -> conflict-free b128
    __shared__ float g_s[32][8];
    __shared__ float cx_s[64];

    const int tid  = threadIdx.x;
    const int h0   = blockIdx.x * 2;
    const int nl   = tid & 7;          // gate*2 + hl
    const int gate = nl >> 1;
    const int hl   = nl & 1;
    const int b    = tid >> 3;         // 0..31
    const int wrow = gate * H_ + h0 + hl;

    // stage this block's 8 W_hh rows into LDS (coalesced, 8 float4 per thread)
#pragma unroll
    for (int i = 0; i < 8; ++i) {
        int idx = tid + i * 256;       // 0..2047 float4 slots
        int rl  = idx >> 8;            // 0..7
        int k4  = idx & 255;
        int rg  = (rl >> 1) * H_ + h0 + (rl & 1);
        float4 v = *reinterpret_cast<const float4*>(W_hh + (size_t)rg * H_ + (k4 << 2));
        *reinterpret_cast<float4*>(&Wl[rl][k4 << 2]) = v;
    }
    // hx0 gather (this block's h-slice) + cx = 0
    if (tid < 64) {
        int bb = tid >> 1;
        int h  = h0 + (tid & 1);
        int sl = sent_len[bb];
        hx0[bb * H_ + h] = hidden_state[((size_t)bb * T_ + (sl - 1)) * H_ + h];
        cx_s[tid] = 0.f;
    }
    grid_barrier(bar, bar + 1);        // hx0 visible everywhere; Wl loaded

    const float4* wr4 = reinterpret_cast<const float4*>(&Wl[nl][0]);

    for (int t = 0; t < T_; ++t) {
        const float* hin = (t & 1) ? hx1 : hx0;
        float*      hout = (t & 1) ? hx0 : hx1;
        const float4* h4 = reinterpret_cast<const float4*>(hin + b * H_);
        float4 s = make_float4(0.f, 0.f, 0.f, 0.f);
#pragma unroll 8
        for (int k = 0; k < H_ / 4; ++k) {
            float4 w = wr4[k];
            float4 a = h4[k];
            s.x = fmaf(w.x, a.x, s.x); s.y = fmaf(w.y, a.y, s.y);
            s.z = fmaf(w.z, a.z, s.z); s.w = fmaf(w.w, a.w, s.w);
        }
        float acc = (s.x + s.y) + (s.z + s.w);
        acc += xg[((size_t)t * B_ + b) * G4 + wrow];
        g_s[b][nl] = acc;
        __syncthreads();
        if (tid < 64) {                // 32 b x 2 h pointwise updates
            int bb  = tid >> 1;
            int hl2 = tid & 1;
            float iv = g_s[bb][0 + hl2];
            float fv = g_s[bb][2 + hl2];
            float gv = g_s[bb][4 + hl2];
            float ov = g_s[bb][6 + hl2];
            float is = 1.f / (1.f + expf(-iv));
            float fs = 1.f / (1.f + expf(-fv));
            float gt = tanhf(gv);
            float os = 1.f / (1.f + expf(-ov));
            float c  = fs * cx_s[tid] + is * gt;
            float hn = os * tanhf(c);
            cx_s[tid] = c;
            int hh = h0 + hl2;
            hout[bb * H_ + hh]                  = hn;
            hs[((size_t)t * B_ + bb) * H_ + hh] = hn;
        }
        grid_barrier(bar, bar + 1);    // hout visible; g_s/cx safe to overwrite
    }
}

// ---------------------------------------------------------------------------
// Row-wise argmax over V=32000; lowest index wins ties.  (unchanged)
// ---------------------------------------------------------------------------
__global__ __launch_bounds__(256)
void argmax_k(const float* __restrict__ logits, float* __restrict__ outi)
{
    __shared__ float sv[256];
    __shared__ int   si[256];
    int r = blockIdx.x;
    const float* row = logits + (size_t)r * V_;
    float best = -INFINITY;
    int   bi   = 0;
    for (int v = threadIdx.x; v < V_; v += 256) {
        float x = row[v];
        if (x > best) { best = x; bi = v; }
    }
    sv[threadIdx.x] = best; si[threadIdx.x] = bi;
    __syncthreads();
    for (int s = 128; s > 0; s >>= 1) {
        if (threadIdx.x < s) {
            float ov = sv[threadIdx.x + s]; int oi = si[threadIdx.x + s];
            if (ov > sv[threadIdx.x] ||
                (ov == sv[threadIdx.x] && oi < si[threadIdx.x])) {
                sv[threadIdx.x] = ov; si[threadIdx.x] = oi;
            }
        }
        __syncthreads();
    }
    if (threadIdx.x == 0) outi[r] = (float)si[0];
}

// ---------------------------------------------------------------------------
extern "C" void kernel_launch(void* const* d_in, const int* in_sizes, int n_in,
                              void* d_out, int out_size, void* d_ws, size_t ws_size,
                              hipStream_t stream)
{
    const int*   sent_inputs  = (const int*)  d_in[0];
    const float* hidden_state = (const float*)d_in[1];
    const int*   sent_len     = (const int*)  d_in[2];
    // d_in[3] = teacher_forcing_ratio (always 1, teacher forcing hard-coded)
    const float* embedding    = (const float*)d_in[4];
    const float* W_ih         = (const float*)d_in[5];
    const float* W_hh         = (const float*)d_in[6];
    const float* b_ih         = (const float*)d_in[7];
    const float* b_hh         = (const float*)d_in[8];
    const float* W_out        = (const float*)d_in[9];
    const float* b_out        = (const float*)d_in[10];
    float* out = (float*)d_out;

    // workspace layout (floats): xg | hs | hx0 | hx1 | bar   (~31.7 MB)
    float* ws  = (float*)d_ws;
    float* xg  = ws;                               // T*B*4096
    float* hs  = xg  + (size_t)T_ * B_ * G4;       // T*B*H
    float* hx0 = hs  + (size_t)T_ * B_ * H_;       // B*H
    float* hx1 = hx0 + B_ * H_;                    // B*H
    unsigned* bar = (unsigned*)(hx1 + B_ * H_);    // 2 x u32 barrier state

    dim3 blk(256);
    gemm_xg<<<dim3(12, 32), blk, 0, stream>>>(sent_inputs, embedding, W_ih, b_ih, b_hh, xg);
    hipMemsetAsync(bar, 0, 2 * sizeof(unsigned), stream);

    void* kargs[8];
    kargs[0] = (void*)&W_hh;
    kargs[1] = (void*)&xg;
    kargs[2] = (void*)&hidden_state;
    kargs[3] = (void*)&sent_len;
    kargs[4] = (void*)&hs;
    kargs[5] = (void*)&hx0;
    kargs[6] = (void*)&hx1;
    kargs[7] = (void*)&bar;
    hipLaunchCooperativeKernel((void*)lstm_fused, dim3(LBLK), dim3(256), kargs, 0, stream);

    gemm_logits<<<dim3(12, 250), blk, 0, stream>>>(hs, W_out, b_out, out);
    argmax_k<<<dim3(B_ * T_), blk, 0, stream>>>(out, out + (size_t)B_ * T_ * V_);
}

// Round 2
// 3490.211 us; speedup vs baseline: 1.4813x; 1.4813x over previous
//
#include <hip/hip_runtime.h>
#include <math.h>

#define B_  32
#define T_  48
#define H_  1024
#define D_  512
#define V_  32000
#define G4  4096   // 4*H
#define LBLK 512   // blocks in fused LSTM (each owns 2 h-values x 4 gates = 8 W_hh rows)

// ---------------------------------------------------------------------------
// Tiled fp32 GEMM #1: x_gates.  (unchanged)
//   out xg[r = t*B+b][n] = dot(embedding[tok(b,t)], W_ih[n]) + b_ih[n]+b_hh[n]
//   M=1536, N=4096, K=512. 128x128 tile, BK=16, 256 thr, 8x8 microtile (4+4).
// ---------------------------------------------------------------------------
__global__ __launch_bounds__(256)
void gemm_xg(const int* __restrict__ sent_inputs,
             const float* __restrict__ embedding,
             const float* __restrict__ W_ih,
             const float* __restrict__ b_ih,
             const float* __restrict__ b_hh,
             float* __restrict__ xg)
{
    __shared__ float As[16][132];
    __shared__ float Bs[16][132];
    __shared__ int   rowoff[128];

    const int tid = threadIdx.x;
    const int rb  = blockIdx.x * 128;
    const int nb  = blockIdx.y * 128;

    if (tid < 128) {
        int r   = rb + tid;
        int t   = r >> 5;
        int b   = r & 31;
        int tok = sent_inputs[b * T_ + t];
        rowoff[tid] = tok * D_;
    }
    __syncthreads();

    const int ty = tid >> 4, tx = tid & 15;
    float acc[8][8];
#pragma unroll
    for (int i = 0; i < 8; ++i)
#pragma unroll
        for (int j = 0; j < 8; ++j) acc[i][j] = 0.f;

    for (int it = 0; it < D_ / 16; ++it) {
        const int k0 = it * 16;
        __syncthreads();
#pragma unroll
        for (int j = 0; j < 2; ++j) {
            int i  = tid + j * 256;
            int m  = i >> 2;
            int kk = (i & 3) << 2;
            float4 av = *reinterpret_cast<const float4*>(embedding + rowoff[m] + k0 + kk);
            As[kk+0][m] = av.x; As[kk+1][m] = av.y; As[kk+2][m] = av.z; As[kk+3][m] = av.w;
            float4 bv = *reinterpret_cast<const float4*>(W_ih + (size_t)(nb + m) * D_ + k0 + kk);
            Bs[kk+0][m] = bv.x; Bs[kk+1][m] = bv.y; Bs[kk+2][m] = bv.z; Bs[kk+3][m] = bv.w;
        }
        __syncthreads();
#pragma unroll
        for (int kk = 0; kk < 16; ++kk) {
            float4 a0 = *reinterpret_cast<const float4*>(&As[kk][ty * 4]);
            float4 a1 = *reinterpret_cast<const float4*>(&As[kk][64 + ty * 4]);
            float4 b0 = *reinterpret_cast<const float4*>(&Bs[kk][tx * 4]);
            float4 b1 = *reinterpret_cast<const float4*>(&Bs[kk][64 + tx * 4]);
            float a[8] = {a0.x,a0.y,a0.z,a0.w,a1.x,a1.y,a1.z,a1.w};
            float b[8] = {b0.x,b0.y,b0.z,b0.w,b1.x,b1.y,b1.z,b1.w};
#pragma unroll
            for (int i = 0; i < 8; ++i)
#pragma unroll
                for (int j = 0; j < 8; ++j) acc[i][j] = fmaf(a[i], b[j], acc[i][j]);
        }
    }

    float bias[8];
#pragma unroll
    for (int j = 0; j < 8; ++j) {
        int n = nb + ((j < 4) ? tx * 4 + j : 64 + tx * 4 + (j - 4));
        bias[j] = b_ih[n] + b_hh[n];
    }
#pragma unroll
    for (int i = 0; i < 8; ++i) {
        int m = (i < 4) ? ty * 4 + i : 64 + ty * 4 + (i - 4);
        int r = rb + m;
        float* op = xg + (size_t)r * G4 + nb;
        float4 v0 = make_float4(acc[i][0]+bias[0], acc[i][1]+bias[1],
                                acc[i][2]+bias[2], acc[i][3]+bias[3]);
        float4 v1 = make_float4(acc[i][4]+bias[4], acc[i][5]+bias[5],
                                acc[i][6]+bias[6], acc[i][7]+bias[7]);
        *reinterpret_cast<float4*>(op + tx * 4)      = v0;
        *reinterpret_cast<float4*>(op + 64 + tx * 4) = v1;
    }
}

// ---------------------------------------------------------------------------
// Tiled fp32 GEMM #2: logits.  (unchanged)
// ---------------------------------------------------------------------------
__global__ __launch_bounds__(256)
void gemm_logits(const float* __restrict__ hs,
                 const float* __restrict__ W_out,
                 const float* __restrict__ b_out,
                 float* __restrict__ out)
{
    __shared__ float As[16][132];
    __shared__ float Bs[16][132];
    __shared__ int   rowoff[128];

    const int tid = threadIdx.x;
    const int rb  = blockIdx.x * 128;
    const int nb  = blockIdx.y * 128;

    if (tid < 128) {
        int r = rb + tid;
        int b = r / T_;
        int t = r - b * T_;
        rowoff[tid] = (t * B_ + b) * H_;
    }
    __syncthreads();

    const int ty = tid >> 4, tx = tid & 15;
    float acc[8][8];
#pragma unroll
    for (int i = 0; i < 8; ++i)
#pragma unroll
        for (int j = 0; j < 8; ++j) acc[i][j] = 0.f;

    for (int it = 0; it < H_ / 16; ++it) {
        const int k0 = it * 16;
        __syncthreads();
#pragma unroll
        for (int j = 0; j < 2; ++j) {
            int i  = tid + j * 256;
            int m  = i >> 2;
            int kk = (i & 3) << 2;
            float4 av = *reinterpret_cast<const float4*>(hs + rowoff[m] + k0 + kk);
            As[kk+0][m] = av.x; As[kk+1][m] = av.y; As[kk+2][m] = av.z; As[kk+3][m] = av.w;
            float4 bv = *reinterpret_cast<const float4*>(W_out + (size_t)(nb + m) * H_ + k0 + kk);
            Bs[kk+0][m] = bv.x; Bs[kk+1][m] = bv.y; Bs[kk+2][m] = bv.z; Bs[kk+3][m] = bv.w;
        }
        __syncthreads();
#pragma unroll
        for (int kk = 0; kk < 16; ++kk) {
            float4 a0 = *reinterpret_cast<const float4*>(&As[kk][ty * 4]);
            float4 a1 = *reinterpret_cast<const float4*>(&As[kk][64 + ty * 4]);
            float4 b0 = *reinterpret_cast<const float4*>(&Bs[kk][tx * 4]);
            float4 b1 = *reinterpret_cast<const float4*>(&Bs[kk][64 + tx * 4]);
            float a[8] = {a0.x,a0.y,a0.z,a0.w,a1.x,a1.y,a1.z,a1.w};
            float b[8] = {b0.x,b0.y,b0.z,b0.w,b1.x,b1.y,b1.z,b1.w};
#pragma unroll
            for (int i = 0; i < 8; ++i)
#pragma unroll
                for (int j = 0; j < 8; ++j) acc[i][j] = fmaf(a[i], b[j], acc[i][j]);
        }
    }

    float bias[8];
#pragma unroll
    for (int j = 0; j < 8; ++j) {
        int n = nb + ((j < 4) ? tx * 4 + j : 64 + tx * 4 + (j - 4));
        bias[j] = b_out[n];
    }
#pragma unroll
    for (int i = 0; i < 8; ++i) {
        int m = (i < 4) ? ty * 4 + i : 64 + ty * 4 + (i - 4);
        int r = rb + m;
        float* op = out + (size_t)r * V_ + nb;
        float4 v0 = make_float4(acc[i][0]+bias[0], acc[i][1]+bias[1],
                                acc[i][2]+bias[2], acc[i][3]+bias[3]);
        float4 v1 = make_float4(acc[i][4]+bias[4], acc[i][5]+bias[5],
                                acc[i][6]+bias[6], acc[i][7]+bias[7]);
        *reinterpret_cast<float4*>(op + tx * 4)      = v0;
        *reinterpret_cast<float4*>(op + 64 + tx * 4) = v1;
    }
}

// ---------------------------------------------------------------------------
// Contention-free device-wide barrier (no atomic RMW).
//  - arrival: each block does ONE __threadfence (wbl2+inv) then a RELAXED
//    write-through store of `phase` to its own flag slot (no line contention,
//    no per-op cache maintenance).
//  - block 0 is the master: its 256 threads sweep the 512 flags with RELAXED
//    read-through loads, then one fence, then publish `gen = phase`.
//  - other blocks spin on `gen` with RELAXED loads + s_sleep, then one fence.
// phase increases monotonically (no ABA, no reset).
// ---------------------------------------------------------------------------
__device__ __forceinline__ void grid_sync(unsigned* __restrict__ flags,
                                          unsigned* __restrict__ gen,
                                          unsigned phase)
{
    __syncthreads();                       // all waves in block done (vmcnt drained)
    if (blockIdx.x == 0) {
        // master: first make own data device-visible, then sweep arrivals
        if (threadIdx.x == 0) __threadfence();
        for (int i = threadIdx.x; i < LBLK; i += 256) {
            if (i == 0) continue;
            while (__hip_atomic_load(flags + i, __ATOMIC_RELAXED,
                                     __HIP_MEMORY_SCOPE_AGENT) < phase)
                __builtin_amdgcn_s_sleep(1);
        }
        __syncthreads();
        if (threadIdx.x == 0) {
            __threadfence();               // acquire others' data / release own
            __hip_atomic_store(gen, phase, __ATOMIC_RELAXED,
                               __HIP_MEMORY_SCOPE_AGENT);
        }
        __syncthreads();
    } else {
        if (threadIdx.x == 0) {
            __threadfence();               // release: flush this XCD's dirty lines
            __hip_atomic_store(flags + blockIdx.x, phase, __ATOMIC_RELAXED,
                               __HIP_MEMORY_SCOPE_AGENT);
            while (__hip_atomic_load(gen, __ATOMIC_RELAXED,
                                     __HIP_MEMORY_SCOPE_AGENT) < phase)
                __builtin_amdgcn_s_sleep(4);
            __threadfence();               // acquire: invalidate stale caches
        }
        __syncthreads();
    }
}

// ---------------------------------------------------------------------------
// Persistent fused LSTM: all 48 steps in one cooperative kernel.
// 512 blocks x 256 thr. Block owns h0=blockIdx*2 (2 h-values x 4 gates =
// 8 W_hh rows), pinned in LDS for the whole recurrence ([8][1028] pad ->
// conflict-free broadcast ds_read_b128). cx lives in LDS. hx ping-pongs
// hx0<->hx1 in global. Math identical to the per-step kernel (float4
// component FMA chains, final (x+y)+(z+w)) -> bit-identical results.
// ---------------------------------------------------------------------------
__global__ __launch_bounds__(256)
void lstm_fused(const float* __restrict__ W_hh,
                const float* __restrict__ xg,
                const float* __restrict__ hidden_state,
                const int* __restrict__ sent_len,
                float* __restrict__ hs,
                float* __restrict__ hx0,
                float* __restrict__ hx1,
                unsigned* __restrict__ bar)   // bar[0..511]=flags, bar[512]=gen
{
    __shared__ float Wl[8][1028];
    __shared__ float g_s[32][8];
    __shared__ float cx_s[64];

    unsigned* flags = bar;
    unsigned* gen   = bar + LBLK;

    const int tid  = threadIdx.x;
    const int h0   = blockIdx.x * 2;
    const int nl   = tid & 7;          // gate*2 + hl
    const int gate = nl >> 1;
    const int hl   = nl & 1;
    const int b    = tid >> 3;         // 0..31
    const int wrow = gate * H_ + h0 + hl;

    // stage this block's 8 W_hh rows into LDS (coalesced, 8 float4 per thread)
#pragma unroll
    for (int i = 0; i < 8; ++i) {
        int idx = tid + i * 256;       // 0..2047 float4 slots
        int rl  = idx >> 8;            // 0..7
        int k4  = idx & 255;
        int rg  = (rl >> 1) * H_ + h0 + (rl & 1);
        float4 v = *reinterpret_cast<const float4*>(W_hh + (size_t)rg * H_ + (k4 << 2));
        *reinterpret_cast<float4*>(&Wl[rl][k4 << 2]) = v;
    }
    // hx0 gather (this block's h-slice) + cx = 0
    if (tid < 64) {
        int bb = tid >> 1;
        int h  = h0 + (tid & 1);
        int sl = sent_len[bb];
        hx0[bb * H_ + h] = hidden_state[((size_t)bb * T_ + (sl - 1)) * H_ + h];
        cx_s[tid] = 0.f;
    }
    unsigned phase = 1;
    grid_sync(flags, gen, phase);      // hx0 visible everywhere; Wl loaded

    const float4* wr4 = reinterpret_cast<const float4*>(&Wl[nl][0]);

    for (int t = 0; t < T_; ++t) {
        const float* hin = (t & 1) ? hx1 : hx0;
        float*      hout = (t & 1) ? hx0 : hx1;
        const float4* h4 = reinterpret_cast<const float4*>(hin + b * H_);
        float4 s = make_float4(0.f, 0.f, 0.f, 0.f);
#pragma unroll 8
        for (int k = 0; k < H_ / 4; ++k) {
            float4 w = wr4[k];
            float4 a = h4[k];
            s.x = fmaf(w.x, a.x, s.x); s.y = fmaf(w.y, a.y, s.y);
            s.z = fmaf(w.z, a.z, s.z); s.w = fmaf(w.w, a.w, s.w);
        }
        float acc = (s.x + s.y) + (s.z + s.w);
        acc += xg[((size_t)t * B_ + b) * G4 + wrow];
        g_s[b][nl] = acc;
        __syncthreads();
        if (tid < 64) {                // 32 b x 2 h pointwise updates
            int bb  = tid >> 1;
            int hl2 = tid & 1;
            float iv = g_s[bb][0 + hl2];
            float fv = g_s[bb][2 + hl2];
            float gv = g_s[bb][4 + hl2];
            float ov = g_s[bb][6 + hl2];
            float is = 1.f / (1.f + expf(-iv));
            float fs = 1.f / (1.f + expf(-fv));
            float gt = tanhf(gv);
            float os = 1.f / (1.f + expf(-ov));
            float c  = fs * cx_s[tid] + is * gt;
            float hn = os * tanhf(c);
            cx_s[tid] = c;
            int hh = h0 + hl2;
            hout[bb * H_ + hh]                  = hn;
            hs[((size_t)t * B_ + bb) * H_ + hh] = hn;
        }
        ++phase;
        grid_sync(flags, gen, phase);  // hout visible; g_s/cx safe to overwrite
    }
}

// ---------------------------------------------------------------------------
// Row-wise argmax over V=32000; lowest index wins ties.  (unchanged)
// ---------------------------------------------------------------------------
__global__ __launch_bounds__(256)
void argmax_k(const float* __restrict__ logits, float* __restrict__ outi)
{
    __shared__ float sv[256];
    __shared__ int   si[256];
    int r = blockIdx.x;
    const float* row = logits + (size_t)r * V_;
    float best = -INFINITY;
    int   bi   = 0;
    for (int v = threadIdx.x; v < V_; v += 256) {
        float x = row[v];
        if (x > best) { best = x; bi = v; }
    }
    sv[threadIdx.x] = best; si[threadIdx.x] = bi;
    __syncthreads();
    for (int s = 128; s > 0; s >>= 1) {
        if (threadIdx.x < s) {
            float ov = sv[threadIdx.x + s]; int oi = si[threadIdx.x + s];
            if (ov > sv[threadIdx.x] ||
                (ov == sv[threadIdx.x] && oi < si[threadIdx.x])) {
                sv[threadIdx.x] = ov; si[threadIdx.x] = oi;
            }
        }
        __syncthreads();
    }
    if (threadIdx.x == 0) outi[r] = (float)si[0];
}

// ---------------------------------------------------------------------------
extern "C" void kernel_launch(void* const* d_in, const int* in_sizes, int n_in,
                              void* d_out, int out_size, void* d_ws, size_t ws_size,
                              hipStream_t stream)
{
    const int*   sent_inputs  = (const int*)  d_in[0];
    const float* hidden_state = (const float*)d_in[1];
    const int*   sent_len     = (const int*)  d_in[2];
    // d_in[3] = teacher_forcing_ratio (always 1, teacher forcing hard-coded)
    const float* embedding    = (const float*)d_in[4];
    const float* W_ih         = (const float*)d_in[5];
    const float* W_hh         = (const float*)d_in[6];
    const float* b_ih         = (const float*)d_in[7];
    const float* b_hh         = (const float*)d_in[8];
    const float* W_out        = (const float*)d_in[9];
    const float* b_out        = (const float*)d_in[10];
    float* out = (float*)d_out;

    // workspace layout (floats): xg | hs | hx0 | hx1 | bar   (~31.7 MB)
    float* ws  = (float*)d_ws;
    float* xg  = ws;                               // T*B*4096
    float* hs  = xg  + (size_t)T_ * B_ * G4;       // T*B*H
    float* hx0 = hs  + (size_t)T_ * B_ * H_;       // B*H
    float* hx1 = hx0 + B_ * H_;                    // B*H
    unsigned* bar = (unsigned*)(hx1 + B_ * H_);    // flags[512] + gen

    dim3 blk(256);
    gemm_xg<<<dim3(12, 32), blk, 0, stream>>>(sent_inputs, embedding, W_ih, b_ih, b_hh, xg);
    hipMemsetAsync(bar, 0, (LBLK + 1) * sizeof(unsigned), stream);

    void* kargs[8];
    kargs[0] = (void*)&W_hh;
    kargs[1] = (void*)&xg;
    kargs[2] = (void*)&hidden_state;
    kargs[3] = (void*)&sent_len;
    kargs[4] = (void*)&hs;
    kargs[5] = (void*)&hx0;
    kargs[6] = (void*)&hx1;
    kargs[7] = (void*)&bar;
    hipLaunchCooperativeKernel((void*)lstm_fused, dim3(LBLK), dim3(256), kargs, 0, stream);

    gemm_logits<<<dim3(12, 250), blk, 0, stream>>>(hs, W_out, b_out, out);
    argmax_k<<<dim3(B_ * T_), blk, 0, stream>>>(out, out + (size_t)B_ * T_ * V_);
}

// Round 3
// 2568.453 us; speedup vs baseline: 2.0129x; 1.3589x over previous
//
#include <hip/hip_runtime.h>
#include <math.h>

#define B_  32
#define T_  48
#define H_  1024
#define D_  512
#define V_  32000
#define G4  4096   // 4*H
#define LBLK 512   // blocks in fused LSTM (each owns 2 h-values x 4 gates = 8 W_hh rows)

// ---------------------------------------------------------------------------
// Tiled fp32 GEMM #1: x_gates.  (unchanged)
//   out xg[r = t*B+b][n] = dot(embedding[tok(b,t)], W_ih[n]) + b_ih[n]+b_hh[n]
//   M=1536, N=4096, K=512. 128x128 tile, BK=16, 256 thr, 8x8 microtile (4+4).
// ---------------------------------------------------------------------------
__global__ __launch_bounds__(256)
void gemm_xg(const int* __restrict__ sent_inputs,
             const float* __restrict__ embedding,
             const float* __restrict__ W_ih,
             const float* __restrict__ b_ih,
             const float* __restrict__ b_hh,
             float* __restrict__ xg)
{
    __shared__ float As[16][132];
    __shared__ float Bs[16][132];
    __shared__ int   rowoff[128];

    const int tid = threadIdx.x;
    const int rb  = blockIdx.x * 128;
    const int nb  = blockIdx.y * 128;

    if (tid < 128) {
        int r   = rb + tid;
        int t   = r >> 5;
        int b   = r & 31;
        int tok = sent_inputs[b * T_ + t];
        rowoff[tid] = tok * D_;
    }
    __syncthreads();

    const int ty = tid >> 4, tx = tid & 15;
    float acc[8][8];
#pragma unroll
    for (int i = 0; i < 8; ++i)
#pragma unroll
        for (int j = 0; j < 8; ++j) acc[i][j] = 0.f;

    for (int it = 0; it < D_ / 16; ++it) {
        const int k0 = it * 16;
        __syncthreads();
#pragma unroll
        for (int j = 0; j < 2; ++j) {
            int i  = tid + j * 256;
            int m  = i >> 2;
            int kk = (i & 3) << 2;
            float4 av = *reinterpret_cast<const float4*>(embedding + rowoff[m] + k0 + kk);
            As[kk+0][m] = av.x; As[kk+1][m] = av.y; As[kk+2][m] = av.z; As[kk+3][m] = av.w;
            float4 bv = *reinterpret_cast<const float4*>(W_ih + (size_t)(nb + m) * D_ + k0 + kk);
            Bs[kk+0][m] = bv.x; Bs[kk+1][m] = bv.y; Bs[kk+2][m] = bv.z; Bs[kk+3][m] = bv.w;
        }
        __syncthreads();
#pragma unroll
        for (int kk = 0; kk < 16; ++kk) {
            float4 a0 = *reinterpret_cast<const float4*>(&As[kk][ty * 4]);
            float4 a1 = *reinterpret_cast<const float4*>(&As[kk][64 + ty * 4]);
            float4 b0 = *reinterpret_cast<const float4*>(&Bs[kk][tx * 4]);
            float4 b1 = *reinterpret_cast<const float4*>(&Bs[kk][64 + tx * 4]);
            float a[8] = {a0.x,a0.y,a0.z,a0.w,a1.x,a1.y,a1.z,a1.w};
            float b[8] = {b0.x,b0.y,b0.z,b0.w,b1.x,b1.y,b1.z,b1.w};
#pragma unroll
            for (int i = 0; i < 8; ++i)
#pragma unroll
                for (int j = 0; j < 8; ++j) acc[i][j] = fmaf(a[i], b[j], acc[i][j]);
        }
    }

    float bias[8];
#pragma unroll
    for (int j = 0; j < 8; ++j) {
        int n = nb + ((j < 4) ? tx * 4 + j : 64 + tx * 4 + (j - 4));
        bias[j] = b_ih[n] + b_hh[n];
    }
#pragma unroll
    for (int i = 0; i < 8; ++i) {
        int m = (i < 4) ? ty * 4 + i : 64 + ty * 4 + (i - 4);
        int r = rb + m;
        float* op = xg + (size_t)r * G4 + nb;
        float4 v0 = make_float4(acc[i][0]+bias[0], acc[i][1]+bias[1],
                                acc[i][2]+bias[2], acc[i][3]+bias[3]);
        float4 v1 = make_float4(acc[i][4]+bias[4], acc[i][5]+bias[5],
                                acc[i][6]+bias[6], acc[i][7]+bias[7]);
        *reinterpret_cast<float4*>(op + tx * 4)      = v0;
        *reinterpret_cast<float4*>(op + 64 + tx * 4) = v1;
    }
}

// ---------------------------------------------------------------------------
// Tiled fp32 GEMM #2: logits.  (unchanged)
// ---------------------------------------------------------------------------
__global__ __launch_bounds__(256)
void gemm_logits(const float* __restrict__ hs,
                 const float* __restrict__ W_out,
                 const float* __restrict__ b_out,
                 float* __restrict__ out)
{
    __shared__ float As[16][132];
    __shared__ float Bs[16][132];
    __shared__ int   rowoff[128];

    const int tid = threadIdx.x;
    const int rb  = blockIdx.x * 128;
    const int nb  = blockIdx.y * 128;

    if (tid < 128) {
        int r = rb + tid;
        int b = r / T_;
        int t = r - b * T_;
        rowoff[tid] = (t * B_ + b) * H_;
    }
    __syncthreads();

    const int ty = tid >> 4, tx = tid & 15;
    float acc[8][8];
#pragma unroll
    for (int i = 0; i < 8; ++i)
#pragma unroll
        for (int j = 0; j < 8; ++j) acc[i][j] = 0.f;

    for (int it = 0; it < H_ / 16; ++it) {
        const int k0 = it * 16;
        __syncthreads();
#pragma unroll
        for (int j = 0; j < 2; ++j) {
            int i  = tid + j * 256;
            int m  = i >> 2;
            int kk = (i & 3) << 2;
            float4 av = *reinterpret_cast<const float4*>(hs + rowoff[m] + k0 + kk);
            As[kk+0][m] = av.x; As[kk+1][m] = av.y; As[kk+2][m] = av.z; As[kk+3][m] = av.w;
            float4 bv = *reinterpret_cast<const float4*>(W_out + (size_t)(nb + m) * H_ + k0 + kk);
            Bs[kk+0][m] = bv.x; Bs[kk+1][m] = bv.y; Bs[kk+2][m] = bv.z; Bs[kk+3][m] = bv.w;
        }
        __syncthreads();
#pragma unroll
        for (int kk = 0; kk < 16; ++kk) {
            float4 a0 = *reinterpret_cast<const float4*>(&As[kk][ty * 4]);
            float4 a1 = *reinterpret_cast<const float4*>(&As[kk][64 + ty * 4]);
            float4 b0 = *reinterpret_cast<const float4*>(&Bs[kk][tx * 4]);
            float4 b1 = *reinterpret_cast<const float4*>(&Bs[kk][64 + tx * 4]);
            float a[8] = {a0.x,a0.y,a0.z,a0.w,a1.x,a1.y,a1.z,a1.w};
            float b[8] = {b0.x,b0.y,b0.z,b0.w,b1.x,b1.y,b1.z,b1.w};
#pragma unroll
            for (int i = 0; i < 8; ++i)
#pragma unroll
                for (int j = 0; j < 8; ++j) acc[i][j] = fmaf(a[i], b[j], acc[i][j]);
        }
    }

    float bias[8];
#pragma unroll
    for (int j = 0; j < 8; ++j) {
        int n = nb + ((j < 4) ? tx * 4 + j : 64 + tx * 4 + (j - 4));
        bias[j] = b_out[n];
    }
#pragma unroll
    for (int i = 0; i < 8; ++i) {
        int m = (i < 4) ? ty * 4 + i : 64 + ty * 4 + (i - 4);
        int r = rb + m;
        float* op = out + (size_t)r * V_ + nb;
        float4 v0 = make_float4(acc[i][0]+bias[0], acc[i][1]+bias[1],
                                acc[i][2]+bias[2], acc[i][3]+bias[3]);
        float4 v1 = make_float4(acc[i][4]+bias[4], acc[i][5]+bias[5],
                                acc[i][6]+bias[6], acc[i][7]+bias[7]);
        *reinterpret_cast<float4*>(op + tx * 4)      = v0;
        *reinterpret_cast<float4*>(op + 64 + tx * 4) = v1;
    }
}

// ---------------------------------------------------------------------------
// Fence-free device-wide barrier.
// Correctness model: all cross-block data (hs slices, hx0) is WRITE-ONCE per
// launch and published with relaxed agent-scope (sc1, write-through) stores,
// so no L2 can ever hold a stale copy -> no buffer_wbl2 / buffer_inv needed.
// __syncthreads drains each wave's vmcnt before s_barrier, so all of the
// block's sc1 stores are globally visible before the flag store issues.
// Arrival: one relaxed sc1 store to flags[blockIdx]. Wait: all 256 threads
// poll 2 flags each (read-only, no line ownership ping-pong). Flags are
// monotonic (no reset / no ABA).
// ---------------------------------------------------------------------------
__device__ __forceinline__ void grid_sync(unsigned* __restrict__ flags,
                                          unsigned phase)
{
    __syncthreads();                       // all waves' sc1 stores drained
    if (threadIdx.x == 0)
        __hip_atomic_store(flags + blockIdx.x, phase, __ATOMIC_RELAXED,
                           __HIP_MEMORY_SCOPE_AGENT);
    for (int i = threadIdx.x; i < LBLK; i += 256) {
        while (__hip_atomic_load(flags + i, __ATOMIC_RELAXED,
                                 __HIP_MEMORY_SCOPE_AGENT) < phase)
            __builtin_amdgcn_s_sleep(2);
    }
    __syncthreads();
    asm volatile("" ::: "memory");         // no load hoisting into poll region
}

// ---------------------------------------------------------------------------
// Persistent fused LSTM: all 48 steps in one cooperative kernel.
// 512 blocks x 256 thr. Block owns h0=blockIdx*2 (2 h-values x 4 gates =
// 8 W_hh rows), pinned in LDS ([8][1028] pad -> conflict-free broadcast
// ds_read_b128). cx lives in LDS.
// The hx chain IS hs: step t reads hs[t-1] (hx0 for t=0) and writes hs[t]
// with relaxed agent (sc1, write-through) stores -> every hx address is
// written exactly once, readers demand-fetch the current value from L3,
// and L2s never need invalidation. Gate math identical to the per-step
// kernel (float4 component FMA chains, final (x+y)+(z+w)) -> bit-identical.
// ---------------------------------------------------------------------------
__global__ __launch_bounds__(256)
void lstm_fused(const float* __restrict__ W_hh,
                const float* __restrict__ xg,
                const float* __restrict__ hidden_state,
                const int* __restrict__ sent_len,
                float* __restrict__ hs,       // [T][B][H] = hx chain
                float* __restrict__ hx0,      // [B][H] initial hx
                unsigned* __restrict__ flags) // [LBLK]
{
    __shared__ float Wl[8][1028];
    __shared__ float g_s[32][8];
    __shared__ float cx_s[64];

    const int tid  = threadIdx.x;
    const int h0   = blockIdx.x * 2;
    const int nl   = tid & 7;          // gate*2 + hl
    const int gate = nl >> 1;
    const int hl   = nl & 1;
    const int b    = tid >> 3;         // 0..31
    const int wrow = gate * H_ + h0 + hl;

    // stage this block's 8 W_hh rows into LDS (coalesced, 8 float4 per thread)
#pragma unroll
    for (int i = 0; i < 8; ++i) {
        int idx = tid + i * 256;       // 0..2047 float4 slots
        int rl  = idx >> 8;            // 0..7
        int k4  = idx & 255;
        int rg  = (rl >> 1) * H_ + h0 + (rl & 1);
        float4 v = *reinterpret_cast<const float4*>(W_hh + (size_t)rg * H_ + (k4 << 2));
        *reinterpret_cast<float4*>(&Wl[rl][k4 << 2]) = v;
    }
    // hx0 gather (this block's 2-h slice, disjoint across blocks) + cx = 0
    if (tid < 64) {
        int bb = tid >> 1;
        int h  = h0 + (tid & 1);
        int sl = sent_len[bb];
        float v = hidden_state[((size_t)bb * T_ + (sl - 1)) * H_ + h];
        __hip_atomic_store(hx0 + bb * H_ + h, v, __ATOMIC_RELAXED,
                           __HIP_MEMORY_SCOPE_AGENT);
        cx_s[tid] = 0.f;
    }
    unsigned phase = 1;
    grid_sync(flags, phase);           // hx0 + all Wl visible

    const float4* wr4 = reinterpret_cast<const float4*>(&Wl[nl][0]);

    for (int t = 0; t < T_; ++t) {
        const float* hin = (t == 0) ? hx0 : hs + (size_t)(t - 1) * B_ * H_;
        const float4* h4 = reinterpret_cast<const float4*>(hin + b * H_);
        float4 s = make_float4(0.f, 0.f, 0.f, 0.f);
#pragma unroll 8
        for (int k = 0; k < H_ / 4; ++k) {
            float4 w = wr4[k];
            float4 a = h4[k];
            s.x = fmaf(w.x, a.x, s.x); s.y = fmaf(w.y, a.y, s.y);
            s.z = fmaf(w.z, a.z, s.z); s.w = fmaf(w.w, a.w, s.w);
        }
        float acc = (s.x + s.y) + (s.z + s.w);
        acc += xg[((size_t)t * B_ + b) * G4 + wrow];
        g_s[b][nl] = acc;
        __syncthreads();
        if (tid < 64) {                // 32 b x 2 h pointwise updates
            int bb  = tid >> 1;
            int hl2 = tid & 1;
            float iv = g_s[bb][0 + hl2];
            float fv = g_s[bb][2 + hl2];
            float gv = g_s[bb][4 + hl2];
            float ov = g_s[bb][6 + hl2];
            float is = 1.f / (1.f + expf(-iv));
            float fs = 1.f / (1.f + expf(-fv));
            float gt = tanhf(gv);
            float os = 1.f / (1.f + expf(-ov));
            float c  = fs * cx_s[tid] + is * gt;
            float hn = os * tanhf(c);
            cx_s[tid] = c;
            int hh = h0 + hl2;
            __hip_atomic_store(hs + ((size_t)t * B_ + bb) * H_ + hh, hn,
                               __ATOMIC_RELAXED, __HIP_MEMORY_SCOPE_AGENT);
        }
        if (t + 1 < T_) {              // last step: kernel-end release covers hs
            ++phase;
            grid_sync(flags, phase);   // hs[t] visible; g_s/cx safe to overwrite
        }
    }
}

// ---------------------------------------------------------------------------
// Row-wise argmax over V=32000; lowest index wins ties.  (unchanged)
// ---------------------------------------------------------------------------
__global__ __launch_bounds__(256)
void argmax_k(const float* __restrict__ logits, float* __restrict__ outi)
{
    __shared__ float sv[256];
    __shared__ int   si[256];
    int r = blockIdx.x;
    const float* row = logits + (size_t)r * V_;
    float best = -INFINITY;
    int   bi   = 0;
    for (int v = threadIdx.x; v < V_; v += 256) {
        float x = row[v];
        if (x > best) { best = x; bi = v; }
    }
    sv[threadIdx.x] = best; si[threadIdx.x] = bi;
    __syncthreads();
    for (int s = 128; s > 0; s >>= 1) {
        if (threadIdx.x < s) {
            float ov = sv[threadIdx.x + s]; int oi = si[threadIdx.x + s];
            if (ov > sv[threadIdx.x] ||
                (ov == sv[threadIdx.x] && oi < si[threadIdx.x])) {
                sv[threadIdx.x] = ov; si[threadIdx.x] = oi;
            }
        }
        __syncthreads();
    }
    if (threadIdx.x == 0) outi[r] = (float)si[0];
}

// ---------------------------------------------------------------------------
extern "C" void kernel_launch(void* const* d_in, const int* in_sizes, int n_in,
                              void* d_out, int out_size, void* d_ws, size_t ws_size,
                              hipStream_t stream)
{
    const int*   sent_inputs  = (const int*)  d_in[0];
    const float* hidden_state = (const float*)d_in[1];
    const int*   sent_len     = (const int*)  d_in[2];
    // d_in[3] = teacher_forcing_ratio (always 1, teacher forcing hard-coded)
    const float* embedding    = (const float*)d_in[4];
    const float* W_ih         = (const float*)d_in[5];
    const float* W_hh         = (const float*)d_in[6];
    const float* b_ih         = (const float*)d_in[7];
    const float* b_hh         = (const float*)d_in[8];
    const float* W_out        = (const float*)d_in[9];
    const float* b_out        = (const float*)d_in[10];
    float* out = (float*)d_out;

    // workspace layout (floats): xg | hs | hx0 | flags   (~31.6 MB)
    float* ws  = (float*)d_ws;
    float* xg  = ws;                               // T*B*4096
    float* hs  = xg  + (size_t)T_ * B_ * G4;       // T*B*H (doubles as hx chain)
    float* hx0 = hs  + (size_t)T_ * B_ * H_;       // B*H
    unsigned* flags = (unsigned*)(hx0 + B_ * H_);  // LBLK x u32

    dim3 blk(256);
    gemm_xg<<<dim3(12, 32), blk, 0, stream>>>(sent_inputs, embedding, W_ih, b_ih, b_hh, xg);
    hipMemsetAsync(flags, 0, LBLK * sizeof(unsigned), stream);

    void* kargs[7];
    kargs[0] = (void*)&W_hh;
    kargs[1] = (void*)&xg;
    kargs[2] = (void*)&hidden_state;
    kargs[3] = (void*)&sent_len;
    kargs[4] = (void*)&hs;
    kargs[5] = (void*)&hx0;
    kargs[6] = (void*)&flags;
    hipLaunchCooperativeKernel((void*)lstm_fused, dim3(LBLK), dim3(256), kargs, 0, stream);

    gemm_logits<<<dim3(12, 250), blk, 0, stream>>>(hs, W_out, b_out, out);
    argmax_k<<<dim3(B_ * T_), blk, 0, stream>>>(out, out + (size_t)B_ * T_ * V_);
}